// Round 15
// baseline (302.411 us; speedup 1.0000x reference)
//
#include <hip/hip_runtime.h>

#define N_NODES 50000
#define N_EDGES 800000
#define DIM 128
#define N_LAYERS 3

// fixed-capacity bucket: 64 ushort slots/node (128 B = exactly 2 lines).
// In-degree ~ Poisson(16); P(>64) ~ 1e-20. src ids < 50000 fit ushort.
#define CAP_LOG2 6
#define CAP (1 << CAP_LOG2)

typedef __attribute__((ext_vector_type(8))) short bf16x8;
typedef __attribute__((ext_vector_type(4))) float f32x4;

__device__ __forceinline__ unsigned short f2bf(float f) {
    unsigned int u = __float_as_uint(f);
    u += 0x7fffu + ((u >> 16) & 1u);   // RNE
    return (unsigned short)(u >> 16);
}
__device__ __forceinline__ float bfu2f_lo(unsigned int v) { return __uint_as_float(v << 16); }
__device__ __forceinline__ float bfu2f_hi(unsigned int v) { return __uint_as_float(v & 0xffff0000u); }

// ---------------- build (XCD-partitioned) + cvt ----------------
// R14 accounting: WRITE 47 MB = z 12.8 + scatter ~4.8 (XCD partition works)
// + ~25.6 MB of atomic fabric ops (800k x >=32 B) — the atomics are the
// floor. ushort slots halve the scatter/agg-index footprint.

#define NODE_RANGE ((N_NODES + 7) / 8)        // 6250 nodes per XCD range
#define EDGES_PER_BLOCK 2048                  // 256 thr x 8 edges
#define BUILD_CH ((N_EDGES + EDGES_PER_BLOCK - 1) / EDGES_PER_BLOCK)   // 391 chunks
#define BUILD_NB (BUILD_CH * 8)               // 3128 blocks
#define CVT_X_T (N_NODES * (DIM / 4))         // 1,600,000 float4s
#define CVT_W_T (6 * DIM * DIM)               // 98,304
#define CVT_NB  ((CVT_X_T + CVT_W_T + 255) / 256)   // 6634

__global__ void build_cvt_kernel(const int* __restrict__ src, const int* __restrict__ dst,
                                 int* __restrict__ counts, unsigned short* __restrict__ srcs_sorted,
                                 const float* __restrict__ x, unsigned short* __restrict__ z,
                                 const float* __restrict__ Ws1, const float* __restrict__ Ws2,
                                 unsigned short* __restrict__ wt) {
    if (blockIdx.x < BUILD_NB) {
        int r = blockIdx.x & 7;               // dst range; aligns with XCD round-robin dispatch
        int c = blockIdx.x >> 3;              // edge chunk
        int lo = r * NODE_RANGE;
        int hi = lo + NODE_RANGE;
        int base = c * EDGES_PER_BLOCK;
#pragma unroll
        for (int j = 0; j < 8; ++j) {
            int e = base + j * 256 + threadIdx.x;
            if (e < N_EDGES) {
                int d = dst[e];
                if (d >= lo && d < hi) {
                    int s = src[e];
                    int rk = atomicAdd(&counts[d], 1);
                    if (rk < CAP) srcs_sorted[(d << CAP_LOG2) + rk] = (unsigned short)s;
                }
            }
        }
    } else {
        int t = (blockIdx.x - BUILD_NB) * 256 + threadIdx.x;
        if (t < CVT_X_T) {
            float4 v = ((const float4*)x)[t];
            ushort4 o;
            o.x = f2bf(v.x); o.y = f2bf(v.y); o.z = f2bf(v.z); o.w = f2bf(v.w);
            ((ushort4*)z)[t] = o;
        } else if (t - CVT_X_T < CVT_W_T) {
            int u = t - CVT_X_T;
            int m = u >> 14;
            int r2 = u & 16383;
            int n = r2 >> 7;
            int k = r2 & 127;
            const float* Wm = (m < 3) ? (Ws1 + (size_t)m * DIM * DIM)
                                      : (Ws2 + (size_t)(m - 3) * DIM * DIM);
            wt[u] = f2bf(Wm[(size_t)k * DIM + n]);   // WT[m][n][k]
        }
    }
}

// ---------------- aggregation ----------------
// One wave per node. sub = lane>>4 (0..3), col = lane&15; lane loads uint4
// (16 B), 16 lanes/row -> one gather instruction fetches FOUR edge rows.
// Indices are ushort: one uint load gives sub its TWO edge ids (even/odd).
// Fold subs: shfl_xor 16/32.

__global__ __launch_bounds__(256) void agg_kernel(const unsigned short* __restrict__ z,
                                                  const int* __restrict__ counts,
                                                  const unsigned short* __restrict__ srcs,
                                                  unsigned short* __restrict__ h) {
    int gid  = blockIdx.x * blockDim.x + threadIdx.x;
    int node = gid >> 6;
    int lane = threadIdx.x & 63;
    int sub  = lane >> 4;
    int col  = lane & 15;
    if (node >= N_NODES) return;
    const uint4* zp = (const uint4*)z;            // row stride = 16 uint4
    const unsigned int* sp = (const unsigned int*)srcs;   // 2 indices per uint

    float a0 = 0.f, a1 = 0.f, a2 = 0.f, a3 = 0.f, a4 = 0.f, a5 = 0.f, a6 = 0.f, a7 = 0.f;
    float b0 = 0.f, b1 = 0.f, b2 = 0.f, b3 = 0.f, b4 = 0.f, b5 = 0.f, b6 = 0.f, b7 = 0.f;

    int s = node << CAP_LOG2;                     // slot base (even)
    int deg = counts[node];
    if (deg > CAP) deg = CAP;
    int e = s + deg;
    int i = s;
    for (; i + 8 <= e; i += 8) {
        unsigned int pair = sp[(i >> 1) + sub];   // edges i+2*sub, i+2*sub+1
        int eA = (int)(pair & 0xffffu);
        int eB = (int)(pair >> 16);
        uint4 vA = zp[(size_t)eA * 16 + col];
        uint4 vB = zp[(size_t)eB * 16 + col];
        a0 += bfu2f_lo(vA.x); a1 += bfu2f_hi(vA.x); a2 += bfu2f_lo(vA.y); a3 += bfu2f_hi(vA.y);
        a4 += bfu2f_lo(vA.z); a5 += bfu2f_hi(vA.z); a6 += bfu2f_lo(vA.w); a7 += bfu2f_hi(vA.w);
        b0 += bfu2f_lo(vB.x); b1 += bfu2f_hi(vB.x); b2 += bfu2f_lo(vB.y); b3 += bfu2f_hi(vB.y);
        b4 += bfu2f_lo(vB.z); b5 += bfu2f_hi(vB.z); b6 += bfu2f_lo(vB.w); b7 += bfu2f_hi(vB.w);
    }
    // tail (0..7 edges): sub handles slots i+2*sub and i+2*sub+1 if in range
    {
        int j0 = i + sub * 2;
        if (j0 < e) {
            int eA = (int)srcs[j0];
            uint4 vA = zp[(size_t)eA * 16 + col];
            a0 += bfu2f_lo(vA.x); a1 += bfu2f_hi(vA.x); a2 += bfu2f_lo(vA.y); a3 += bfu2f_hi(vA.y);
            a4 += bfu2f_lo(vA.z); a5 += bfu2f_hi(vA.z); a6 += bfu2f_lo(vA.w); a7 += bfu2f_hi(vA.w);
        }
        if (j0 + 1 < e) {
            int eB = (int)srcs[j0 + 1];
            uint4 vB = zp[(size_t)eB * 16 + col];
            b0 += bfu2f_lo(vB.x); b1 += bfu2f_hi(vB.x); b2 += bfu2f_lo(vB.y); b3 += bfu2f_hi(vB.y);
            b4 += bfu2f_lo(vB.z); b5 += bfu2f_hi(vB.z); b6 += bfu2f_lo(vB.w); b7 += bfu2f_hi(vB.w);
        }
    }

    a0 += b0; a1 += b1; a2 += b2; a3 += b3; a4 += b4; a5 += b5; a6 += b6; a7 += b7;
    a0 += __shfl_xor(a0, 16); a1 += __shfl_xor(a1, 16); a2 += __shfl_xor(a2, 16); a3 += __shfl_xor(a3, 16);
    a4 += __shfl_xor(a4, 16); a5 += __shfl_xor(a5, 16); a6 += __shfl_xor(a6, 16); a7 += __shfl_xor(a7, 16);
    a0 += __shfl_xor(a0, 32); a1 += __shfl_xor(a1, 32); a2 += __shfl_xor(a2, 32); a3 += __shfl_xor(a3, 32);
    a4 += __shfl_xor(a4, 32); a5 += __shfl_xor(a5, 32); a6 += __shfl_xor(a6, 32); a7 += __shfl_xor(a7, 32);

    // self term (eps = 0)
    uint4 sv = zp[(size_t)node * 16 + col];
    a0 += bfu2f_lo(sv.x); a1 += bfu2f_hi(sv.x); a2 += bfu2f_lo(sv.y); a3 += bfu2f_hi(sv.y);
    a4 += bfu2f_lo(sv.z); a5 += bfu2f_hi(sv.z); a6 += bfu2f_lo(sv.w); a7 += bfu2f_hi(sv.w);

    if (sub == 0) {
        uint4 o;
        o.x = (unsigned int)f2bf(a0) | ((unsigned int)f2bf(a1) << 16);
        o.y = (unsigned int)f2bf(a2) | ((unsigned int)f2bf(a3) << 16);
        o.z = (unsigned int)f2bf(a4) | ((unsigned int)f2bf(a5) << 16);
        o.w = (unsigned int)f2bf(a6) | ((unsigned int)f2bf(a7) << 16);
        ((uint4*)h)[(size_t)node * 16 + col] = o;
    }
}

// ---------------- fused MLP: C = relu(relu(A@W1+b1)@W2+b2) ----------------
// Block = 128 threads (2 waves), 64 rows/block, wave tile 32 rows x 128 cols.

#define T_STRIDE 132

template <bool LAST>
__global__ __launch_bounds__(128) void mlp_fused(const unsigned short* __restrict__ A,
                                                 const unsigned short* __restrict__ WT1,
                                                 const float* __restrict__ b1,
                                                 const unsigned short* __restrict__ WT2,
                                                 const float* __restrict__ b2,
                                                 void* __restrict__ Cout, int M) {
    __shared__ unsigned short t_lds[64 * T_STRIDE];
    int wave = threadIdx.x >> 6;     // 0..1
    int lane = threadIdx.x & 63;
    int quad = lane >> 4;
    int r16  = lane & 15;
    int rowbase = blockIdx.x * 64 + wave * 32;
    int lrow = wave * 32;

    f32x4 acc[2][8];
#pragma unroll
    for (int mt = 0; mt < 2; ++mt)
#pragma unroll
        for (int nt = 0; nt < 8; ++nt)
#pragma unroll
            for (int i = 0; i < 4; ++i) acc[mt][nt][i] = 0.f;

    int ar0 = rowbase + r16;       if (ar0 > M - 1) ar0 = M - 1;
    int ar1 = rowbase + 16 + r16;  if (ar1 > M - 1) ar1 = M - 1;

#pragma unroll
    for (int ks = 0; ks < 4; ++ks) {
        int k = ks * 32 + quad * 8;
        bf16x8 a0 = *(const bf16x8*)(A + (size_t)ar0 * DIM + k);
        bf16x8 a1 = *(const bf16x8*)(A + (size_t)ar1 * DIM + k);
#pragma unroll
        for (int nt = 0; nt < 8; ++nt) {
            bf16x8 b = *(const bf16x8*)(WT1 + (size_t)(nt * 16 + r16) * DIM + k);
            acc[0][nt] = __builtin_amdgcn_mfma_f32_16x16x32_bf16(a0, b, acc[0][nt], 0, 0, 0);
            acc[1][nt] = __builtin_amdgcn_mfma_f32_16x16x32_bf16(a1, b, acc[1][nt], 0, 0, 0);
        }
    }

#pragma unroll
    for (int mt = 0; mt < 2; ++mt)
#pragma unroll
        for (int nt = 0; nt < 8; ++nt) {
            int col = nt * 16 + r16;
            float bv = b1[col];
#pragma unroll
            for (int i = 0; i < 4; ++i) {
                float v = fmaxf(acc[mt][nt][i] + bv, 0.f);
                t_lds[(lrow + mt * 16 + quad * 4 + i) * T_STRIDE + col] = f2bf(v);
            }
        }
    __syncthreads();

    f32x4 acc2[2][8];
#pragma unroll
    for (int mt = 0; mt < 2; ++mt)
#pragma unroll
        for (int nt = 0; nt < 8; ++nt)
#pragma unroll
            for (int i = 0; i < 4; ++i) acc2[mt][nt][i] = 0.f;

#pragma unroll
    for (int ks = 0; ks < 4; ++ks) {
        int k = ks * 32 + quad * 8;
        bf16x8 a0 = *(const bf16x8*)&t_lds[(lrow + r16) * T_STRIDE + k];
        bf16x8 a1 = *(const bf16x8*)&t_lds[(lrow + 16 + r16) * T_STRIDE + k];
#pragma unroll
        for (int nt = 0; nt < 8; ++nt) {
            bf16x8 b = *(const bf16x8*)(WT2 + (size_t)(nt * 16 + r16) * DIM + k);
            acc2[0][nt] = __builtin_amdgcn_mfma_f32_16x16x32_bf16(a0, b, acc2[0][nt], 0, 0, 0);
            acc2[1][nt] = __builtin_amdgcn_mfma_f32_16x16x32_bf16(a1, b, acc2[1][nt], 0, 0, 0);
        }
    }

#pragma unroll
    for (int mt = 0; mt < 2; ++mt)
#pragma unroll
        for (int nt = 0; nt < 8; ++nt) {
            int col = nt * 16 + r16;
            float bv = b2[col];
#pragma unroll
            for (int i = 0; i < 4; ++i) {
                int row = rowbase + mt * 16 + quad * 4 + i;
                if (row < M) {
                    float v = fmaxf(acc2[mt][nt][i] + bv, 0.f);
                    if (LAST) __builtin_nontemporal_store(v, &((float*)Cout)[(size_t)row * DIM + col]);
                    else ((unsigned short*)Cout)[(size_t)row * DIM + col] = f2bf(v);
                }
            }
        }
}

// ---------------- launch ----------------

extern "C" void kernel_launch(void* const* d_in, const int* in_sizes, int n_in,
                              void* d_out, int out_size, void* d_ws, size_t ws_size,
                              hipStream_t stream) {
    const float* x   = (const float*)d_in[0];
    const float* Ws1 = (const float*)d_in[1];
    const float* bs1 = (const float*)d_in[2];
    const float* Ws2 = (const float*)d_in[3];
    const float* bs2 = (const float*)d_in[4];
    const int*   ei  = (const int*)d_in[5];   // int32 (JAX x64 disabled)
    const int* src = ei;
    const int* dst = ei + N_EDGES;
    float* out = (float*)d_out;

    char* ws = (char*)d_ws;
    size_t off = 0;
    auto carve = [&](size_t bytes) {
        void* p = ws + off;
        off += (bytes + 255) & ~(size_t)255;
        return p;
    };
    unsigned short* zA   = (unsigned short*)carve((size_t)N_NODES * DIM * 2);
    unsigned short* zB   = (unsigned short*)carve((size_t)N_NODES * DIM * 2);
    unsigned short* bufh = (unsigned short*)carve((size_t)N_NODES * DIM * 2);
    unsigned short* wt   = (unsigned short*)carve((size_t)6 * DIM * DIM * 2);
    int* counts = (int*)carve((size_t)N_NODES * 4);
    unsigned short* srcs = (unsigned short*)carve((size_t)N_NODES * CAP * 2);   // 6.4 MB buckets

    // build (XCD-partitioned hist+scatter) + cvt
    hipMemsetAsync(counts, 0, (size_t)N_NODES * 4, stream);
    build_cvt_kernel<<<BUILD_NB + CVT_NB, 256, 0, stream>>>(src, dst, counts, srcs,
                                                            x, zA, Ws1, Ws2, wt);

    const int agg_grid = (N_NODES * 64 + 255) / 256;
    const int mlp_grid = (N_NODES + 63) / 64;

    unsigned short* zin = zA;
    unsigned short* znext = zB;
    for (int l = 0; l < N_LAYERS; ++l) {
        agg_kernel<<<agg_grid, 256, 0, stream>>>(zin, counts, srcs, bufh);
        if (l == N_LAYERS - 1) {
            mlp_fused<true><<<mlp_grid, 128, 0, stream>>>(
                bufh, wt + (size_t)l * DIM * DIM, bs1 + (size_t)l * DIM,
                wt + (size_t)(3 + l) * DIM * DIM, bs2 + (size_t)l * DIM, out, N_NODES);
        } else {
            mlp_fused<false><<<mlp_grid, 128, 0, stream>>>(
                bufh, wt + (size_t)l * DIM * DIM, bs1 + (size_t)l * DIM,
                wt + (size_t)(3 + l) * DIM * DIM, bs2 + (size_t)l * DIM, znext, N_NODES);
            unsigned short* tmp = zin; zin = znext; znext = tmp;
        }
    }
}

// Round 16
// 290.148 us; speedup vs baseline: 1.0423x; 1.0423x over previous
//
#include <hip/hip_runtime.h>

#define N_NODES 50000
#define N_EDGES 800000
#define DIM 128
#define N_LAYERS 3

// fixed-capacity bucket: 64 ushort slots/node (128 B = exactly 2 lines).
// In-degree ~ Poisson(16); P(>64) ~ 1e-20. src ids < 50000 fit ushort.
#define CAP_LOG2 6
#define CAP (1 << CAP_LOG2)

typedef __attribute__((ext_vector_type(8))) short bf16x8;
typedef __attribute__((ext_vector_type(4))) float f32x4;

__device__ __forceinline__ unsigned short f2bf(float f) {
    unsigned int u = __float_as_uint(f);
    u += 0x7fffu + ((u >> 16) & 1u);   // RNE
    return (unsigned short)(u >> 16);
}
__device__ __forceinline__ float bfu2f_lo(unsigned int v) { return __uint_as_float(v << 16); }
__device__ __forceinline__ float bfu2f_hi(unsigned int v) { return __uint_as_float(v & 0xffff0000u); }

// ---------------- build (XCD-partitioned) + cvt ----------------
// Build floor = the 800k atomics themselves (~25 MB fabric ops); scatter WB
// already minimized by the XCD partition (R13/R14). Do not touch further.

#define NODE_RANGE ((N_NODES + 7) / 8)        // 6250 nodes per XCD range
#define EDGES_PER_BLOCK 2048                  // 256 thr x 8 edges
#define BUILD_CH ((N_EDGES + EDGES_PER_BLOCK - 1) / EDGES_PER_BLOCK)   // 391 chunks
#define BUILD_NB (BUILD_CH * 8)               // 3128 blocks
#define CVT_X_T (N_NODES * (DIM / 4))         // 1,600,000 float4s
#define CVT_W_T (6 * DIM * DIM)               // 98,304
#define CVT_NB  ((CVT_X_T + CVT_W_T + 255) / 256)   // 6634

__global__ void build_cvt_kernel(const int* __restrict__ src, const int* __restrict__ dst,
                                 int* __restrict__ counts, unsigned short* __restrict__ srcs_sorted,
                                 const float* __restrict__ x, unsigned short* __restrict__ z,
                                 const float* __restrict__ Ws1, const float* __restrict__ Ws2,
                                 unsigned short* __restrict__ wt) {
    if (blockIdx.x < BUILD_NB) {
        int r = blockIdx.x & 7;               // dst range; aligns with XCD round-robin dispatch
        int c = blockIdx.x >> 3;              // edge chunk
        int lo = r * NODE_RANGE;
        int hi = lo + NODE_RANGE;
        int base = c * EDGES_PER_BLOCK;
#pragma unroll
        for (int j = 0; j < 8; ++j) {
            int e = base + j * 256 + threadIdx.x;
            if (e < N_EDGES) {
                int d = dst[e];
                if (d >= lo && d < hi) {
                    int s = src[e];
                    int rk = atomicAdd(&counts[d], 1);
                    if (rk < CAP) srcs_sorted[(d << CAP_LOG2) + rk] = (unsigned short)s;
                }
            }
        }
    } else {
        int t = (blockIdx.x - BUILD_NB) * 256 + threadIdx.x;
        if (t < CVT_X_T) {
            float4 v = ((const float4*)x)[t];
            ushort4 o;
            o.x = f2bf(v.x); o.y = f2bf(v.y); o.z = f2bf(v.z); o.w = f2bf(v.w);
            ((ushort4*)z)[t] = o;
        } else if (t - CVT_X_T < CVT_W_T) {
            int u = t - CVT_X_T;
            int m = u >> 14;
            int r2 = u & 16383;
            int n = r2 >> 7;
            int k = r2 & 127;
            const float* Wm = (m < 3) ? (Ws1 + (size_t)m * DIM * DIM)
                                      : (Ws2 + (size_t)(m - 3) * DIM * DIM);
            wt[u] = f2bf(Wm[(size_t)k * DIM + n]);   // WT[m][n][k]
        }
    }
}

// ---------------- aggregation (unchanged; near transaction floor) ----------------

__global__ __launch_bounds__(256) void agg_kernel(const unsigned short* __restrict__ z,
                                                  const int* __restrict__ counts,
                                                  const unsigned short* __restrict__ srcs,
                                                  unsigned short* __restrict__ h) {
    int gid  = blockIdx.x * blockDim.x + threadIdx.x;
    int node = gid >> 6;
    int lane = threadIdx.x & 63;
    int sub  = lane >> 4;
    int col  = lane & 15;
    if (node >= N_NODES) return;
    const uint4* zp = (const uint4*)z;            // row stride = 16 uint4
    const unsigned int* sp = (const unsigned int*)srcs;   // 2 indices per uint

    float a0 = 0.f, a1 = 0.f, a2 = 0.f, a3 = 0.f, a4 = 0.f, a5 = 0.f, a6 = 0.f, a7 = 0.f;
    float b0 = 0.f, b1 = 0.f, b2 = 0.f, b3 = 0.f, b4 = 0.f, b5 = 0.f, b6 = 0.f, b7 = 0.f;

    int s = node << CAP_LOG2;                     // slot base (even)
    int deg = counts[node];
    if (deg > CAP) deg = CAP;
    int e = s + deg;
    int i = s;
    for (; i + 8 <= e; i += 8) {
        unsigned int pair = sp[(i >> 1) + sub];   // edges i+2*sub, i+2*sub+1
        int eA = (int)(pair & 0xffffu);
        int eB = (int)(pair >> 16);
        uint4 vA = zp[(size_t)eA * 16 + col];
        uint4 vB = zp[(size_t)eB * 16 + col];
        a0 += bfu2f_lo(vA.x); a1 += bfu2f_hi(vA.x); a2 += bfu2f_lo(vA.y); a3 += bfu2f_hi(vA.y);
        a4 += bfu2f_lo(vA.z); a5 += bfu2f_hi(vA.z); a6 += bfu2f_lo(vA.w); a7 += bfu2f_hi(vA.w);
        b0 += bfu2f_lo(vB.x); b1 += bfu2f_hi(vB.x); b2 += bfu2f_lo(vB.y); b3 += bfu2f_hi(vB.y);
        b4 += bfu2f_lo(vB.z); b5 += bfu2f_hi(vB.z); b6 += bfu2f_lo(vB.w); b7 += bfu2f_hi(vB.w);
    }
    // tail (0..7 edges): sub handles slots i+2*sub and i+2*sub+1 if in range
    {
        int j0 = i + sub * 2;
        if (j0 < e) {
            int eA = (int)srcs[j0];
            uint4 vA = zp[(size_t)eA * 16 + col];
            a0 += bfu2f_lo(vA.x); a1 += bfu2f_hi(vA.x); a2 += bfu2f_lo(vA.y); a3 += bfu2f_hi(vA.y);
            a4 += bfu2f_lo(vA.z); a5 += bfu2f_hi(vA.z); a6 += bfu2f_lo(vA.w); a7 += bfu2f_hi(vA.w);
        }
        if (j0 + 1 < e) {
            int eB = (int)srcs[j0 + 1];
            uint4 vB = zp[(size_t)eB * 16 + col];
            b0 += bfu2f_lo(vB.x); b1 += bfu2f_hi(vB.x); b2 += bfu2f_lo(vB.y); b3 += bfu2f_hi(vB.y);
            b4 += bfu2f_lo(vB.z); b5 += bfu2f_hi(vB.z); b6 += bfu2f_lo(vB.w); b7 += bfu2f_hi(vB.w);
        }
    }

    a0 += b0; a1 += b1; a2 += b2; a3 += b3; a4 += b4; a5 += b5; a6 += b6; a7 += b7;
    a0 += __shfl_xor(a0, 16); a1 += __shfl_xor(a1, 16); a2 += __shfl_xor(a2, 16); a3 += __shfl_xor(a3, 16);
    a4 += __shfl_xor(a4, 16); a5 += __shfl_xor(a5, 16); a6 += __shfl_xor(a6, 16); a7 += __shfl_xor(a7, 16);
    a0 += __shfl_xor(a0, 32); a1 += __shfl_xor(a1, 32); a2 += __shfl_xor(a2, 32); a3 += __shfl_xor(a3, 32);
    a4 += __shfl_xor(a4, 32); a5 += __shfl_xor(a5, 32); a6 += __shfl_xor(a6, 32); a7 += __shfl_xor(a7, 32);

    // self term (eps = 0)
    uint4 sv = zp[(size_t)node * 16 + col];
    a0 += bfu2f_lo(sv.x); a1 += bfu2f_hi(sv.x); a2 += bfu2f_lo(sv.y); a3 += bfu2f_hi(sv.y);
    a4 += bfu2f_lo(sv.z); a5 += bfu2f_hi(sv.z); a6 += bfu2f_lo(sv.w); a7 += bfu2f_hi(sv.w);

    if (sub == 0) {
        uint4 o;
        o.x = (unsigned int)f2bf(a0) | ((unsigned int)f2bf(a1) << 16);
        o.y = (unsigned int)f2bf(a2) | ((unsigned int)f2bf(a3) << 16);
        o.z = (unsigned int)f2bf(a4) | ((unsigned int)f2bf(a5) << 16);
        o.w = (unsigned int)f2bf(a6) | ((unsigned int)f2bf(a7) << 16);
        ((uint4*)h)[(size_t)node * 16 + col] = o;
    }
}

// ---------------- fused MLP: C = relu(relu(A@W1+b1)@W2+b2) ----------------
// R15 fix: 1564 waves (1.5/SIMD) couldn't hide WT load latency. Now:
// block = 256 thr (4 waves) over a 64-row x 128-col tile; wave tile is
// 32 rows x 64 cols (2x2 wave grid) -> 3128 waves (~12/CU), half the VGPR
// accumulator, same total MFMA work.

#define T_STRIDE 132

template <bool LAST>
__global__ __launch_bounds__(256) void mlp_fused(const unsigned short* __restrict__ A,
                                                 const unsigned short* __restrict__ WT1,
                                                 const float* __restrict__ b1,
                                                 const unsigned short* __restrict__ WT2,
                                                 const float* __restrict__ b2,
                                                 void* __restrict__ Cout, int M) {
    __shared__ unsigned short t_lds[64 * T_STRIDE];
    int wave = threadIdx.x >> 6;     // 0..3
    int lane = threadIdx.x & 63;
    int quad = lane >> 4;
    int r16  = lane & 15;
    int wm = (wave & 1) * 32;        // row half within block
    int wn = (wave >> 1) * 64;       // col half
    int rowbase = blockIdx.x * 64 + wm;

    f32x4 acc[2][4];
#pragma unroll
    for (int mt = 0; mt < 2; ++mt)
#pragma unroll
        for (int nt = 0; nt < 4; ++nt)
#pragma unroll
            for (int i = 0; i < 4; ++i) acc[mt][nt][i] = 0.f;

    int ar0 = rowbase + r16;       if (ar0 > M - 1) ar0 = M - 1;
    int ar1 = rowbase + 16 + r16;  if (ar1 > M - 1) ar1 = M - 1;

#pragma unroll
    for (int ks = 0; ks < 4; ++ks) {
        int k = ks * 32 + quad * 8;
        bf16x8 a0 = *(const bf16x8*)(A + (size_t)ar0 * DIM + k);
        bf16x8 a1 = *(const bf16x8*)(A + (size_t)ar1 * DIM + k);
#pragma unroll
        for (int nt = 0; nt < 4; ++nt) {
            int col = wn + nt * 16 + r16;
            bf16x8 b = *(const bf16x8*)(WT1 + (size_t)col * DIM + k);
            acc[0][nt] = __builtin_amdgcn_mfma_f32_16x16x32_bf16(a0, b, acc[0][nt], 0, 0, 0);
            acc[1][nt] = __builtin_amdgcn_mfma_f32_16x16x32_bf16(a1, b, acc[1][nt], 0, 0, 0);
        }
    }

#pragma unroll
    for (int mt = 0; mt < 2; ++mt)
#pragma unroll
        for (int nt = 0; nt < 4; ++nt) {
            int col = wn + nt * 16 + r16;
            float bv = b1[col];
#pragma unroll
            for (int i = 0; i < 4; ++i) {
                float v = fmaxf(acc[mt][nt][i] + bv, 0.f);
                t_lds[(wm + mt * 16 + quad * 4 + i) * T_STRIDE + col] = f2bf(v);
            }
        }
    __syncthreads();

    f32x4 acc2[2][4];
#pragma unroll
    for (int mt = 0; mt < 2; ++mt)
#pragma unroll
        for (int nt = 0; nt < 4; ++nt)
#pragma unroll
            for (int i = 0; i < 4; ++i) acc2[mt][nt][i] = 0.f;

#pragma unroll
    for (int ks = 0; ks < 4; ++ks) {
        int k = ks * 32 + quad * 8;
        bf16x8 a0 = *(const bf16x8*)&t_lds[(wm + r16) * T_STRIDE + k];
        bf16x8 a1 = *(const bf16x8*)&t_lds[(wm + 16 + r16) * T_STRIDE + k];
#pragma unroll
        for (int nt = 0; nt < 4; ++nt) {
            int col = wn + nt * 16 + r16;
            bf16x8 b = *(const bf16x8*)(WT2 + (size_t)col * DIM + k);
            acc2[0][nt] = __builtin_amdgcn_mfma_f32_16x16x32_bf16(a0, b, acc2[0][nt], 0, 0, 0);
            acc2[1][nt] = __builtin_amdgcn_mfma_f32_16x16x32_bf16(a1, b, acc2[1][nt], 0, 0, 0);
        }
    }

#pragma unroll
    for (int mt = 0; mt < 2; ++mt)
#pragma unroll
        for (int nt = 0; nt < 4; ++nt) {
            int col = wn + nt * 16 + r16;
            float bv = b2[col];
#pragma unroll
            for (int i = 0; i < 4; ++i) {
                int row = rowbase + mt * 16 + quad * 4 + i;
                if (row < M) {
                    float v = fmaxf(acc2[mt][nt][i] + bv, 0.f);
                    if (LAST) __builtin_nontemporal_store(v, &((float*)Cout)[(size_t)row * DIM + col]);
                    else ((unsigned short*)Cout)[(size_t)row * DIM + col] = f2bf(v);
                }
            }
        }
}

// ---------------- launch ----------------

extern "C" void kernel_launch(void* const* d_in, const int* in_sizes, int n_in,
                              void* d_out, int out_size, void* d_ws, size_t ws_size,
                              hipStream_t stream) {
    const float* x   = (const float*)d_in[0];
    const float* Ws1 = (const float*)d_in[1];
    const float* bs1 = (const float*)d_in[2];
    const float* Ws2 = (const float*)d_in[3];
    const float* bs2 = (const float*)d_in[4];
    const int*   ei  = (const int*)d_in[5];   // int32 (JAX x64 disabled)
    const int* src = ei;
    const int* dst = ei + N_EDGES;
    float* out = (float*)d_out;

    char* ws = (char*)d_ws;
    size_t off = 0;
    auto carve = [&](size_t bytes) {
        void* p = ws + off;
        off += (bytes + 255) & ~(size_t)255;
        return p;
    };
    unsigned short* zA   = (unsigned short*)carve((size_t)N_NODES * DIM * 2);
    unsigned short* zB   = (unsigned short*)carve((size_t)N_NODES * DIM * 2);
    unsigned short* bufh = (unsigned short*)carve((size_t)N_NODES * DIM * 2);
    unsigned short* wt   = (unsigned short*)carve((size_t)6 * DIM * DIM * 2);
    int* counts = (int*)carve((size_t)N_NODES * 4);
    unsigned short* srcs = (unsigned short*)carve((size_t)N_NODES * CAP * 2);   // 6.4 MB buckets

    // build (XCD-partitioned hist+scatter) + cvt
    hipMemsetAsync(counts, 0, (size_t)N_NODES * 4, stream);
    build_cvt_kernel<<<BUILD_NB + CVT_NB, 256, 0, stream>>>(src, dst, counts, srcs,
                                                            x, zA, Ws1, Ws2, wt);

    const int agg_grid = (N_NODES * 64 + 255) / 256;
    const int mlp_grid = (N_NODES + 63) / 64;

    unsigned short* zin = zA;
    unsigned short* znext = zB;
    for (int l = 0; l < N_LAYERS; ++l) {
        agg_kernel<<<agg_grid, 256, 0, stream>>>(zin, counts, srcs, bufh);
        if (l == N_LAYERS - 1) {
            mlp_fused<true><<<mlp_grid, 256, 0, stream>>>(
                bufh, wt + (size_t)l * DIM * DIM, bs1 + (size_t)l * DIM,
                wt + (size_t)(3 + l) * DIM * DIM, bs2 + (size_t)l * DIM, out, N_NODES);
        } else {
            mlp_fused<false><<<mlp_grid, 256, 0, stream>>>(
                bufh, wt + (size_t)l * DIM * DIM, bs1 + (size_t)l * DIM,
                wt + (size_t)(3 + l) * DIM * DIM, bs2 + (size_t)l * DIM, znext, N_NODES);
            unsigned short* tmp = zin; zin = znext; znext = tmp;
        }
    }
}

// Round 17
// 288.569 us; speedup vs baseline: 1.0480x; 1.0055x over previous
//
#include <hip/hip_runtime.h>

#define N_NODES 50000
#define N_EDGES 800000
#define DIM 128
#define N_LAYERS 3

// fixed-capacity bucket: 64 ushort slots/node (128 B = exactly 2 lines).
// In-degree ~ Poisson(16); P(>64) ~ 1e-20. src ids < 50000 fit ushort.
#define CAP_LOG2 6
#define CAP (1 << CAP_LOG2)

typedef __attribute__((ext_vector_type(8))) short bf16x8;
typedef __attribute__((ext_vector_type(4))) float f32x4;

__device__ __forceinline__ unsigned short f2bf(float f) {
    unsigned int u = __float_as_uint(f);
    u += 0x7fffu + ((u >> 16) & 1u);   // RNE
    return (unsigned short)(u >> 16);
}
__device__ __forceinline__ float bfu2f_lo(unsigned int v) { return __uint_as_float(v << 16); }
__device__ __forceinline__ float bfu2f_hi(unsigned int v) { return __uint_as_float(v & 0xffff0000u); }

// ---------------- build (XCD-partitioned) + cvt ----------------
// Build floor = the 800k rank atomics (~43 µs, invariant under ILP x4/x8,
// overlay, nt on/off, ushort). Frozen.

#define NODE_RANGE ((N_NODES + 7) / 8)        // 6250 nodes per XCD range
#define EDGES_PER_BLOCK 2048                  // 256 thr x 8 edges
#define BUILD_CH ((N_EDGES + EDGES_PER_BLOCK - 1) / EDGES_PER_BLOCK)   // 391 chunks
#define BUILD_NB (BUILD_CH * 8)               // 3128 blocks
#define CVT_X_T (N_NODES * (DIM / 4))         // 1,600,000 float4s
#define CVT_W_T (6 * DIM * DIM)               // 98,304
#define CVT_NB  ((CVT_X_T + CVT_W_T + 255) / 256)   // 6634

__global__ void build_cvt_kernel(const int* __restrict__ src, const int* __restrict__ dst,
                                 int* __restrict__ counts, unsigned short* __restrict__ srcs_sorted,
                                 const float* __restrict__ x, unsigned short* __restrict__ z,
                                 const float* __restrict__ Ws1, const float* __restrict__ Ws2,
                                 unsigned short* __restrict__ wt) {
    if (blockIdx.x < BUILD_NB) {
        int r = blockIdx.x & 7;               // dst range; aligns with XCD round-robin dispatch
        int c = blockIdx.x >> 3;              // edge chunk
        int lo = r * NODE_RANGE;
        int hi = lo + NODE_RANGE;
        int base = c * EDGES_PER_BLOCK;
#pragma unroll
        for (int j = 0; j < 8; ++j) {
            int e = base + j * 256 + threadIdx.x;
            if (e < N_EDGES) {
                int d = dst[e];
                if (d >= lo && d < hi) {
                    int s = src[e];
                    int rk = atomicAdd(&counts[d], 1);
                    if (rk < CAP) srcs_sorted[(d << CAP_LOG2) + rk] = (unsigned short)s;
                }
            }
        }
    } else {
        int t = (blockIdx.x - BUILD_NB) * 256 + threadIdx.x;
        if (t < CVT_X_T) {
            float4 v = ((const float4*)x)[t];
            ushort4 o;
            o.x = f2bf(v.x); o.y = f2bf(v.y); o.z = f2bf(v.z); o.w = f2bf(v.w);
            ((ushort4*)z)[t] = o;
        } else if (t - CVT_X_T < CVT_W_T) {
            int u = t - CVT_X_T;
            int m = u >> 14;
            int r2 = u & 16383;
            int n = r2 >> 7;
            int k = r2 & 127;
            const float* Wm = (m < 3) ? (Ws1 + (size_t)m * DIM * DIM)
                                      : (Ws2 + (size_t)(m - 3) * DIM * DIM);
            wt[u] = f2bf(Wm[(size_t)k * DIM + n]);   // WT[m][n][k]
        }
    }
}

// ---------------- aggregation ----------------
// One wave per node; sub = lane>>4, col = lane&15; lane loads uint4 rows.
// R17 probe: 16-edge main loop -> 4 row loads in flight per lane (vs 2).
// Avg deg 16 hits the main body exactly once.

__global__ __launch_bounds__(256) void agg_kernel(const unsigned short* __restrict__ z,
                                                  const int* __restrict__ counts,
                                                  const unsigned short* __restrict__ srcs,
                                                  unsigned short* __restrict__ h) {
    int gid  = blockIdx.x * blockDim.x + threadIdx.x;
    int node = gid >> 6;
    int lane = threadIdx.x & 63;
    int sub  = lane >> 4;
    int col  = lane & 15;
    if (node >= N_NODES) return;
    const uint4* zp = (const uint4*)z;            // row stride = 16 uint4
    const unsigned int* sp = (const unsigned int*)srcs;   // 2 indices per uint

    float a0 = 0.f, a1 = 0.f, a2 = 0.f, a3 = 0.f, a4 = 0.f, a5 = 0.f, a6 = 0.f, a7 = 0.f;
    float b0 = 0.f, b1 = 0.f, b2 = 0.f, b3 = 0.f, b4 = 0.f, b5 = 0.f, b6 = 0.f, b7 = 0.f;

    int s = node << CAP_LOG2;                     // slot base (even)
    int deg = counts[node];
    if (deg > CAP) deg = CAP;
    int e = s + deg;
    int i = s;
    // 16-edge main loop: 2 pair loads, 4 uint4 row loads in flight per lane
    for (; i + 16 <= e; i += 16) {
        unsigned int p0 = sp[(i >> 1) + sub];         // edges i+2sub, i+2sub+1
        unsigned int p1 = sp[(i >> 1) + 4 + sub];     // edges i+8+2sub, i+8+2sub+1
        int eA0 = (int)(p0 & 0xffffu), eB0 = (int)(p0 >> 16);
        int eA1 = (int)(p1 & 0xffffu), eB1 = (int)(p1 >> 16);
        uint4 vA0 = zp[(size_t)eA0 * 16 + col];
        uint4 vB0 = zp[(size_t)eB0 * 16 + col];
        uint4 vA1 = zp[(size_t)eA1 * 16 + col];
        uint4 vB1 = zp[(size_t)eB1 * 16 + col];
        a0 += bfu2f_lo(vA0.x); a1 += bfu2f_hi(vA0.x); a2 += bfu2f_lo(vA0.y); a3 += bfu2f_hi(vA0.y);
        a4 += bfu2f_lo(vA0.z); a5 += bfu2f_hi(vA0.z); a6 += bfu2f_lo(vA0.w); a7 += bfu2f_hi(vA0.w);
        b0 += bfu2f_lo(vB0.x); b1 += bfu2f_hi(vB0.x); b2 += bfu2f_lo(vB0.y); b3 += bfu2f_hi(vB0.y);
        b4 += bfu2f_lo(vB0.z); b5 += bfu2f_hi(vB0.z); b6 += bfu2f_lo(vB0.w); b7 += bfu2f_hi(vB0.w);
        a0 += bfu2f_lo(vA1.x); a1 += bfu2f_hi(vA1.x); a2 += bfu2f_lo(vA1.y); a3 += bfu2f_hi(vA1.y);
        a4 += bfu2f_lo(vA1.z); a5 += bfu2f_hi(vA1.z); a6 += bfu2f_lo(vA1.w); a7 += bfu2f_hi(vA1.w);
        b0 += bfu2f_lo(vB1.x); b1 += bfu2f_hi(vB1.x); b2 += bfu2f_lo(vB1.y); b3 += bfu2f_hi(vB1.y);
        b4 += bfu2f_lo(vB1.z); b5 += bfu2f_hi(vB1.z); b6 += bfu2f_lo(vB1.w); b7 += bfu2f_hi(vB1.w);
    }
    for (; i + 8 <= e; i += 8) {
        unsigned int pair = sp[(i >> 1) + sub];
        int eA = (int)(pair & 0xffffu);
        int eB = (int)(pair >> 16);
        uint4 vA = zp[(size_t)eA * 16 + col];
        uint4 vB = zp[(size_t)eB * 16 + col];
        a0 += bfu2f_lo(vA.x); a1 += bfu2f_hi(vA.x); a2 += bfu2f_lo(vA.y); a3 += bfu2f_hi(vA.y);
        a4 += bfu2f_lo(vA.z); a5 += bfu2f_hi(vA.z); a6 += bfu2f_lo(vA.w); a7 += bfu2f_hi(vA.w);
        b0 += bfu2f_lo(vB.x); b1 += bfu2f_hi(vB.x); b2 += bfu2f_lo(vB.y); b3 += bfu2f_hi(vB.y);
        b4 += bfu2f_lo(vB.z); b5 += bfu2f_hi(vB.z); b6 += bfu2f_lo(vB.w); b7 += bfu2f_hi(vB.w);
    }
    // tail (0..7 edges): sub handles slots i+2*sub and i+2*sub+1 if in range
    {
        int j0 = i + sub * 2;
        if (j0 < e) {
            int eA = (int)srcs[j0];
            uint4 vA = zp[(size_t)eA * 16 + col];
            a0 += bfu2f_lo(vA.x); a1 += bfu2f_hi(vA.x); a2 += bfu2f_lo(vA.y); a3 += bfu2f_hi(vA.y);
            a4 += bfu2f_lo(vA.z); a5 += bfu2f_hi(vA.z); a6 += bfu2f_lo(vA.w); a7 += bfu2f_hi(vA.w);
        }
        if (j0 + 1 < e) {
            int eB = (int)srcs[j0 + 1];
            uint4 vB = zp[(size_t)eB * 16 + col];
            b0 += bfu2f_lo(vB.x); b1 += bfu2f_hi(vB.x); b2 += bfu2f_lo(vB.y); b3 += bfu2f_hi(vB.y);
            b4 += bfu2f_lo(vB.z); b5 += bfu2f_hi(vB.z); b6 += bfu2f_lo(vB.w); b7 += bfu2f_hi(vB.w);
        }
    }

    a0 += b0; a1 += b1; a2 += b2; a3 += b3; a4 += b4; a5 += b5; a6 += b6; a7 += b7;
    a0 += __shfl_xor(a0, 16); a1 += __shfl_xor(a1, 16); a2 += __shfl_xor(a2, 16); a3 += __shfl_xor(a3, 16);
    a4 += __shfl_xor(a4, 16); a5 += __shfl_xor(a5, 16); a6 += __shfl_xor(a6, 16); a7 += __shfl_xor(a7, 16);
    a0 += __shfl_xor(a0, 32); a1 += __shfl_xor(a1, 32); a2 += __shfl_xor(a2, 32); a3 += __shfl_xor(a3, 32);
    a4 += __shfl_xor(a4, 32); a5 += __shfl_xor(a5, 32); a6 += __shfl_xor(a6, 32); a7 += __shfl_xor(a7, 32);

    // self term (eps = 0)
    uint4 sv = zp[(size_t)node * 16 + col];
    a0 += bfu2f_lo(sv.x); a1 += bfu2f_hi(sv.x); a2 += bfu2f_lo(sv.y); a3 += bfu2f_hi(sv.y);
    a4 += bfu2f_lo(sv.z); a5 += bfu2f_hi(sv.z); a6 += bfu2f_lo(sv.w); a7 += bfu2f_hi(sv.w);

    if (sub == 0) {
        uint4 o;
        o.x = (unsigned int)f2bf(a0) | ((unsigned int)f2bf(a1) << 16);
        o.y = (unsigned int)f2bf(a2) | ((unsigned int)f2bf(a3) << 16);
        o.z = (unsigned int)f2bf(a4) | ((unsigned int)f2bf(a5) << 16);
        o.w = (unsigned int)f2bf(a6) | ((unsigned int)f2bf(a7) << 16);
        ((uint4*)h)[(size_t)node * 16 + col] = o;
    }
}

// ---------------- fused MLP: C = relu(relu(A@W1+b1)@W2+b2) ----------------
// Block = 256 thr (4 waves), 64-row x 128-col tile; wave tile 32x64 (2x2).

#define T_STRIDE 132

template <bool LAST>
__global__ __launch_bounds__(256) void mlp_fused(const unsigned short* __restrict__ A,
                                                 const unsigned short* __restrict__ WT1,
                                                 const float* __restrict__ b1,
                                                 const unsigned short* __restrict__ WT2,
                                                 const float* __restrict__ b2,
                                                 void* __restrict__ Cout, int M) {
    __shared__ unsigned short t_lds[64 * T_STRIDE];
    int wave = threadIdx.x >> 6;     // 0..3
    int lane = threadIdx.x & 63;
    int quad = lane >> 4;
    int r16  = lane & 15;
    int wm = (wave & 1) * 32;        // row half within block
    int wn = (wave >> 1) * 64;       // col half
    int rowbase = blockIdx.x * 64 + wm;

    f32x4 acc[2][4];
#pragma unroll
    for (int mt = 0; mt < 2; ++mt)
#pragma unroll
        for (int nt = 0; nt < 4; ++nt)
#pragma unroll
            for (int i = 0; i < 4; ++i) acc[mt][nt][i] = 0.f;

    int ar0 = rowbase + r16;       if (ar0 > M - 1) ar0 = M - 1;
    int ar1 = rowbase + 16 + r16;  if (ar1 > M - 1) ar1 = M - 1;

#pragma unroll
    for (int ks = 0; ks < 4; ++ks) {
        int k = ks * 32 + quad * 8;
        bf16x8 a0 = *(const bf16x8*)(A + (size_t)ar0 * DIM + k);
        bf16x8 a1 = *(const bf16x8*)(A + (size_t)ar1 * DIM + k);
#pragma unroll
        for (int nt = 0; nt < 4; ++nt) {
            int col = wn + nt * 16 + r16;
            bf16x8 b = *(const bf16x8*)(WT1 + (size_t)col * DIM + k);
            acc[0][nt] = __builtin_amdgcn_mfma_f32_16x16x32_bf16(a0, b, acc[0][nt], 0, 0, 0);
            acc[1][nt] = __builtin_amdgcn_mfma_f32_16x16x32_bf16(a1, b, acc[1][nt], 0, 0, 0);
        }
    }

#pragma unroll
    for (int mt = 0; mt < 2; ++mt)
#pragma unroll
        for (int nt = 0; nt < 4; ++nt) {
            int col = wn + nt * 16 + r16;
            float bv = b1[col];
#pragma unroll
            for (int i = 0; i < 4; ++i) {
                float v = fmaxf(acc[mt][nt][i] + bv, 0.f);
                t_lds[(wm + mt * 16 + quad * 4 + i) * T_STRIDE + col] = f2bf(v);
            }
        }
    __syncthreads();

    f32x4 acc2[2][4];
#pragma unroll
    for (int mt = 0; mt < 2; ++mt)
#pragma unroll
        for (int nt = 0; nt < 4; ++nt)
#pragma unroll
            for (int i = 0; i < 4; ++i) acc2[mt][nt][i] = 0.f;

#pragma unroll
    for (int ks = 0; ks < 4; ++ks) {
        int k = ks * 32 + quad * 8;
        bf16x8 a0 = *(const bf16x8*)&t_lds[(wm + r16) * T_STRIDE + k];
        bf16x8 a1 = *(const bf16x8*)&t_lds[(wm + 16 + r16) * T_STRIDE + k];
#pragma unroll
        for (int nt = 0; nt < 4; ++nt) {
            int col = wn + nt * 16 + r16;
            bf16x8 b = *(const bf16x8*)(WT2 + (size_t)col * DIM + k);
            acc2[0][nt] = __builtin_amdgcn_mfma_f32_16x16x32_bf16(a0, b, acc2[0][nt], 0, 0, 0);
            acc2[1][nt] = __builtin_amdgcn_mfma_f32_16x16x32_bf16(a1, b, acc2[1][nt], 0, 0, 0);
        }
    }

#pragma unroll
    for (int mt = 0; mt < 2; ++mt)
#pragma unroll
        for (int nt = 0; nt < 4; ++nt) {
            int col = wn + nt * 16 + r16;
            float bv = b2[col];
#pragma unroll
            for (int i = 0; i < 4; ++i) {
                int row = rowbase + mt * 16 + quad * 4 + i;
                if (row < M) {
                    float v = fmaxf(acc2[mt][nt][i] + bv, 0.f);
                    if (LAST) __builtin_nontemporal_store(v, &((float*)Cout)[(size_t)row * DIM + col]);
                    else ((unsigned short*)Cout)[(size_t)row * DIM + col] = f2bf(v);
                }
            }
        }
}

// ---------------- launch ----------------

extern "C" void kernel_launch(void* const* d_in, const int* in_sizes, int n_in,
                              void* d_out, int out_size, void* d_ws, size_t ws_size,
                              hipStream_t stream) {
    const float* x   = (const float*)d_in[0];
    const float* Ws1 = (const float*)d_in[1];
    const float* bs1 = (const float*)d_in[2];
    const float* Ws2 = (const float*)d_in[3];
    const float* bs2 = (const float*)d_in[4];
    const int*   ei  = (const int*)d_in[5];   // int32 (JAX x64 disabled)
    const int* src = ei;
    const int* dst = ei + N_EDGES;
    float* out = (float*)d_out;

    char* ws = (char*)d_ws;
    size_t off = 0;
    auto carve = [&](size_t bytes) {
        void* p = ws + off;
        off += (bytes + 255) & ~(size_t)255;
        return p;
    };
    unsigned short* zA   = (unsigned short*)carve((size_t)N_NODES * DIM * 2);
    unsigned short* zB   = (unsigned short*)carve((size_t)N_NODES * DIM * 2);
    unsigned short* bufh = (unsigned short*)carve((size_t)N_NODES * DIM * 2);
    unsigned short* wt   = (unsigned short*)carve((size_t)6 * DIM * DIM * 2);
    int* counts = (int*)carve((size_t)N_NODES * 4);
    unsigned short* srcs = (unsigned short*)carve((size_t)N_NODES * CAP * 2);   // 6.4 MB buckets

    // build (XCD-partitioned hist+scatter) + cvt
    hipMemsetAsync(counts, 0, (size_t)N_NODES * 4, stream);
    build_cvt_kernel<<<BUILD_NB + CVT_NB, 256, 0, stream>>>(src, dst, counts, srcs,
                                                            x, zA, Ws1, Ws2, wt);

    const int agg_grid = (N_NODES * 64 + 255) / 256;
    const int mlp_grid = (N_NODES + 63) / 64;

    unsigned short* zin = zA;
    unsigned short* znext = zB;
    for (int l = 0; l < N_LAYERS; ++l) {
        agg_kernel<<<agg_grid, 256, 0, stream>>>(zin, counts, srcs, bufh);
        if (l == N_LAYERS - 1) {
            mlp_fused<true><<<mlp_grid, 256, 0, stream>>>(
                bufh, wt + (size_t)l * DIM * DIM, bs1 + (size_t)l * DIM,
                wt + (size_t)(3 + l) * DIM * DIM, bs2 + (size_t)l * DIM, out, N_NODES);
        } else {
            mlp_fused<false><<<mlp_grid, 256, 0, stream>>>(
                bufh, wt + (size_t)l * DIM * DIM, bs1 + (size_t)l * DIM,
                wt + (size_t)(3 + l) * DIM * DIM, bs2 + (size_t)l * DIM, znext, N_NODES);
            unsigned short* tmp = zin; zin = znext; znext = tmp;
        }
    }
}